// Round 7
// baseline (56.556 us; speedup 1.0000x reference)
//
#include <hip/hip_runtime.h>

#define HALO 5
#define BAND 256
#define SLOTS 272        // BAND + 2*8 halo cols (8 each side)
#define NTHREADS 320
#define ROWS 32
#define ITERS (ROWS + 2*HALO)   // 42 input rows per strip
#define BATCH 16
#define CH 3
#define H 512
#define W 512
#define HW (H*W)
#define NBLOCKS (BATCH * 2 * 16)  // 16 batch x 2 bands x 16 strips = 512

__device__ __forceinline__ void f4add(float4& a, const float4 b) {
    a.x += b.x; a.y += b.y; a.z += b.z; a.w += b.w;
}

__global__ __launch_bounds__(NTHREADS, 2) void ssim_stream_kernel(
    const float* __restrict__ pred, const float* __restrict__ gt,
    float* __restrict__ partial)
{
    // Double-buffered row of column-box quads (vs), 16B slots, bit3-XOR swizzled.
    __shared__ float4 buf[2][SLOTS];            // 8.7 KB
    __shared__ float red[NTHREADS / 64];

    const int tid = threadIdx.x;
    const int bid = (blockIdx.x & 7) * (NBLOCKS / 8) + (blockIdx.x >> 3); // XCD chunks
    const int b     = bid >> 5;          // batch
    const int band  = (bid >> 4) & 1;    // 256-col band
    const int strip = bid & 15;          // 32-row strip
    const int c0  = band * BAND;
    const int gy0 = strip * ROWS - HALO; // input row at iteration 0

    const float* __restrict__ pb = pred + (size_t)b * (CH * HW);
    const float* __restrict__ gb = gt   + (size_t)b * (CH * HW);

    const int  gx    = c0 - 8 + tid;                    // owned column
    const bool colok = (tid < SLOTS) && ((unsigned)gx < W);
    const int  wslot = tid ^ ((tid >> 3) & 1);          // swizzled write slot

    float4 ring[11];
    #pragma unroll
    for (int u = 0; u < 11; ++u) ring[u] = make_float4(0.f, 0.f, 0.f, 0.f);
    float4 vs = make_float4(0.f, 0.f, 0.f, 0.f);
    float accl = 0.f;

    // prefetch input row for iteration 0
    float p0, p1, p2, g0, g1, g2;
    {
        const int gi = gy0;
        if (colok && (unsigned)gi < H) {
            const float* pr = pb + (size_t)gi * W + gx;
            const float* gr = gb + (size_t)gi * W + gx;
            p0 = pr[0]; p1 = pr[HW]; p2 = pr[2 * HW];
            g0 = gr[0]; g1 = gr[HW]; g2 = gr[2 * HW];
        } else { p0 = p1 = p2 = g0 = g1 = g2 = 0.f; }
    }

    const float inv_n = 1.f / 363.f, inv_nm1 = 1.f / 362.f;
    const float c1 = 1e-4f, c2v = 9e-4f;

    for (int basei = 0; basei < ITERS; basei += 11) {
        #pragma unroll
        for (int u = 0; u < 11; ++u) {     // u IS the ring index (static)
            const int ri = basei + u;
            if (ri < ITERS) {
                // ---- consume prefetched row -> channel-reduced quad ----
                float4 q;
                q.x = p0 + p1 + p2;
                q.y = g0 + g1 + g2;
                q.z = fmaf(p0, p0, fmaf(p1, p1, fmaf(p2, p2,
                      fmaf(g0, g0, fmaf(g1, g1, g2 * g2)))));
                q.w = fmaf(p0, g0, fmaf(p1, g1, p2 * g2));
                // ---- prefetch next row (hides under h-phase + barrier) ----
                {
                    const int gi = gy0 + ri + 1;
                    if (colok && (unsigned)gi < H) {
                        const float* pr = pb + (size_t)gi * W + gx;
                        const float* gr = gb + (size_t)gi * W + gx;
                        p0 = pr[0]; p1 = pr[HW]; p2 = pr[2 * HW];
                        g0 = gr[0]; g1 = gr[HW]; g2 = gr[2 * HW];
                    } else { p0 = p1 = p2 = g0 = g1 = g2 = 0.f; }
                }
                // ---- running vertical box (11 rows) in registers ----
                vs.x += q.x - ring[u].x;
                vs.y += q.y - ring[u].y;
                vs.z += q.z - ring[u].z;
                vs.w += q.w - ring[u].w;
                ring[u] = q;
                if (tid < SLOTS) buf[ri & 1][wslot] = vs;
                __syncthreads();
                // ---- horizontal 11-tap + SSIM: 2 output cols per thread ----
                if (ri >= 10 && tid < 128) {
                    const int jb = 2 * tid + 3;
                    #define LRD(j) buf[ri & 1][(j) ^ (((j) >> 3) & 1)]
                    const float4 first = LRD(jb);
                    float4 s = first;
                    #pragma unroll
                    for (int k = 1; k < 11; ++k) f4add(s, LRD(jb + k));
                    {
                        const float mu_p = s.x * inv_n, mu_g = s.y * inv_n;
                        const float varsum = (s.z - s.x * mu_p - s.y * mu_g) * inv_nm1;
                        const float cov    = (s.w - s.x * mu_g) * inv_n;
                        const float num = (2.f * mu_p * mu_g + c1) * (2.f * cov + c2v);
                        const float den = (mu_p * mu_p + mu_g * mu_g + c1) * (varsum + c2v);
                        accl = fmaf(num, __builtin_amdgcn_rcpf(den + 1e-8f), accl);
                    }
                    const float4 last = LRD(jb + 11);
                    #undef LRD
                    s.x += last.x - first.x;
                    s.y += last.y - first.y;
                    s.z += last.z - first.z;
                    s.w += last.w - first.w;
                    {
                        const float mu_p = s.x * inv_n, mu_g = s.y * inv_n;
                        const float varsum = (s.z - s.x * mu_p - s.y * mu_g) * inv_nm1;
                        const float cov    = (s.w - s.x * mu_g) * inv_n;
                        const float num = (2.f * mu_p * mu_g + c1) * (2.f * cov + c2v);
                        const float den = (mu_p * mu_p + mu_g * mu_g + c1) * (varsum + c2v);
                        accl = fmaf(num, __builtin_amdgcn_rcpf(den + 1e-8f), accl);
                    }
                }
            }
        }
    }

    // ---- block reduce (5 waves) ----
    #pragma unroll
    for (int off = 32; off > 0; off >>= 1) accl += __shfl_down(accl, off);
    if ((tid & 63) == 0) red[tid >> 6] = accl;
    __syncthreads();
    if (tid == 0) {
        float t = 0.f;
        #pragma unroll
        for (int wv = 0; wv < NTHREADS / 64; ++wv) t += red[wv];
        partial[bid] = t;
    }
}

__global__ __launch_bounds__(256) void ssim_final_reduce(
    const float* __restrict__ partial, float* __restrict__ out)
{
    __shared__ float red[4];
    const int tid = threadIdx.x;
    float s = 0.f;
    for (int i = tid; i < NBLOCKS; i += 256) s += partial[i];
    #pragma unroll
    for (int off = 32; off > 0; off >>= 1) s += __shfl_down(s, off);
    if ((tid & 63) == 0) red[tid >> 6] = s;
    __syncthreads();
    if (tid == 0) {
        const float total = red[0] + red[1] + red[2] + red[3];
        out[0] = 1.0f - total * (1.0f / (float)(BATCH * H * W));
    }
}

extern "C" void kernel_launch(void* const* d_in, const int* in_sizes, int n_in,
                              void* d_out, int out_size, void* d_ws, size_t ws_size,
                              hipStream_t stream) {
    const float* pred = (const float*)d_in[0];
    const float* gt   = (const float*)d_in[1];
    float* out        = (float*)d_out;
    float* partial    = (float*)d_ws;

    ssim_stream_kernel<<<NBLOCKS, NTHREADS, 0, stream>>>(pred, gt, partial);
    ssim_final_reduce<<<1, 256, 0, stream>>>(partial, out);
}

// Round 8
// 28.841 us; speedup vs baseline: 1.9610x; 1.9610x over previous
//
#include <hip/hip_runtime.h>

#define HALO 5
#define TW 54              // output cols per tile
#define IW 64              // input cols per tile (= lanes)
#define IR 42              // input rows per tile (32 out + 10 halo)
#define BATCH 16
#define CH 3
#define H 512
#define W 512
#define HW (H*W)
#define NCT 10             // ceil(512/54) col tiles
#define NST 16             // 512/32 row strips
#define NBLOCKS (BATCH*NST*NCT)   // 2560

__device__ __forceinline__ void f4add(float4& a, const float4 b) {
    a.x += b.x; a.y += b.y; a.z += b.z; a.w += b.w;
}

__global__ __launch_bounds__(64) void ssim_wave_kernel(
    const float* __restrict__ pred, const float* __restrict__ gt,
    float* __restrict__ partial)
{
    // 8-deep rotating buffer of vertical box sums, rotation-swizzled slots.
    __shared__ float4 buf[8][IW];   // 8 KB

    const int lane = threadIdx.x;
    const int bid  = (blockIdx.x & 7) * (NBLOCKS / 8) + (blockIdx.x >> 3);
    const int tc   = bid % NCT;
    const int rest = bid / NCT;
    const int ts   = rest & 15;
    const int b    = rest >> 4;

    const int gx   = tc * TW - HALO + lane;   // owned input column
    const int gy0  = (ts << 5) - HALO;        // input row at ri=0
    const bool colok = (unsigned)gx < W;

    const float* __restrict__ pb = pred + (size_t)b * (CH * HW);
    const float* __restrict__ gb = gt   + (size_t)b * (CH * HW);

    const float inv_n = 1.f/363.f, inv_nm1 = 1.f/362.f;
    const float C1 = 1e-4f, C2 = 9e-4f;

    float4 ring[11];                 // 11-row vertical history (static idx only)
    #pragma unroll
    for (int u = 0; u < 11; ++u) ring[u] = make_float4(0.f,0.f,0.f,0.f);
    float4 vs = make_float4(0.f,0.f,0.f,0.f);   // running 11-row column box
    float pf[2][6];                  // depth-2 row prefetch (static idx only)
    float accl = 0.f;

#define LOADROW(rr, s) do { \
    const int gy_ = gy0 + (rr); \
    const bool ok_ = colok && ((unsigned)gy_ < H) && ((rr) < IR); \
    const size_t off_ = ok_ ? ((size_t)gy_ * W + gx) : 0; \
    pf[s][0] = ok_ ? pb[off_]          : 0.f; \
    pf[s][1] = ok_ ? pb[off_ + HW]     : 0.f; \
    pf[s][2] = ok_ ? pb[off_ + 2*HW]   : 0.f; \
    pf[s][3] = ok_ ? gb[off_]          : 0.f; \
    pf[s][4] = ok_ ? gb[off_ + HW]     : 0.f; \
    pf[s][5] = ok_ ? gb[off_ + 2*HW]   : 0.f; \
} while(0)

#define RS(ri) do { \
    const float p0 = pf[(ri)&1][0], p1 = pf[(ri)&1][1], p2 = pf[(ri)&1][2]; \
    const float g0 = pf[(ri)&1][3], g1 = pf[(ri)&1][4], g2 = pf[(ri)&1][5]; \
    float4 q; \
    q.x = p0 + p1 + p2; \
    q.y = g0 + g1 + g2; \
    q.z = fmaf(p0,p0, fmaf(p1,p1, fmaf(p2,p2, fmaf(g0,g0, fmaf(g1,g1, g2*g2))))); \
    q.w = fmaf(p0,g0, fmaf(p1,g1, p2*g2)); \
    LOADROW((ri)+2, (ri)&1); \
    vs.x += q.x - ring[(ri)%11].x; \
    vs.y += q.y - ring[(ri)%11].y; \
    vs.z += q.z - ring[(ri)%11].z; \
    vs.w += q.w - ring[(ri)%11].w; \
    ring[(ri)%11] = q; \
    if ((ri) >= 10) buf[((ri)-10)&7][(lane + (((ri)-10)&7)) & 63] = vs; \
} while(0)

#define SSIM_ACC(S, oxv) do { \
    if ((unsigned)(oxv) < W) { \
        const float mu_p = (S).x * inv_n, mu_g = (S).y * inv_n; \
        const float varsum = ((S).z - (S).x*mu_p - (S).y*mu_g) * inv_nm1; \
        const float cov    = ((S).w - (S).x*mu_g) * inv_n; \
        const float num = (2.f*mu_p*mu_g + C1) * (2.f*cov + C2); \
        const float den = (mu_p*mu_p + mu_g*mu_g + C1) * (varsum + C2); \
        accl = fmaf(num, __builtin_amdgcn_rcpf(den + 1e-8f), accl); \
    } \
} while(0)

    // Horizontal 11-tap over the 8 buffered vs-rows; lane = (row r, group g).
    // Group g covers local centers 5+7g+s', s'=0..6 (g=7: s'<=4 via j-guard).
    auto phase2 = [&]() {
        const int r  = lane & 7;
        const int g  = lane >> 3;
        const int jb = 7 * g;
        const int ox0 = tc * TW + jb;
        float4 B = buf[r][(jb + r) & 63];
        #pragma unroll
        for (int k = 1; k < 11; ++k) f4add(B, buf[r][(jb + k + r) & 63]);
        SSIM_ACC(B, ox0);
        #pragma unroll
        for (int sp = 1; sp < 7; ++sp) {
            if (jb + 10 + sp <= 63) {   // also implies center valid (c<=58)
                const float4 nw = buf[r][(jb + 10 + sp + r) & 63];
                const float4 od = buf[r][(jb + sp - 1 + r) & 63];
                B.x += nw.x - od.x; B.y += nw.y - od.y;
                B.z += nw.z - od.z; B.w += nw.w - od.w;
                SSIM_ACC(B, ox0 + sp);
            }
        }
    };

    LOADROW(0, 0);
    LOADROW(1, 1);

    RS(0);  RS(1);  RS(2);  RS(3);  RS(4);  RS(5);  RS(6);  RS(7);  RS(8);
    RS(9);  RS(10); RS(11); RS(12); RS(13); RS(14); RS(15); RS(16); RS(17);
    __syncthreads(); phase2(); __syncthreads();
    RS(18); RS(19); RS(20); RS(21); RS(22); RS(23); RS(24); RS(25);
    __syncthreads(); phase2(); __syncthreads();
    RS(26); RS(27); RS(28); RS(29); RS(30); RS(31); RS(32); RS(33);
    __syncthreads(); phase2(); __syncthreads();
    RS(34); RS(35); RS(36); RS(37); RS(38); RS(39); RS(40); RS(41);
    __syncthreads(); phase2();

    // ---- wave reduce ----
    #pragma unroll
    for (int off = 32; off > 0; off >>= 1) accl += __shfl_down(accl, off);
    if (lane == 0) partial[bid] = accl;

#undef LOADROW
#undef RS
#undef SSIM_ACC
}

__global__ __launch_bounds__(256) void ssim_final_reduce(
    const float* __restrict__ partial, float* __restrict__ out)
{
    __shared__ float red[4];
    const int tid = threadIdx.x;
    float s = 0.f;
    for (int i = tid; i < NBLOCKS; i += 256) s += partial[i];
    #pragma unroll
    for (int off = 32; off > 0; off >>= 1) s += __shfl_down(s, off);
    if ((tid & 63) == 0) red[tid >> 6] = s;
    __syncthreads();
    if (tid == 0) {
        const float total = red[0] + red[1] + red[2] + red[3];
        out[0] = 1.0f - total * (1.0f / (float)(BATCH * H * W));
    }
}

extern "C" void kernel_launch(void* const* d_in, const int* in_sizes, int n_in,
                              void* d_out, int out_size, void* d_ws, size_t ws_size,
                              hipStream_t stream) {
    const float* pred = (const float*)d_in[0];
    const float* gt   = (const float*)d_in[1];
    float* out        = (float*)d_out;
    float* partial    = (float*)d_ws;

    ssim_wave_kernel<<<NBLOCKS, 64, 0, stream>>>(pred, gt, partial);
    ssim_final_reduce<<<1, 256, 0, stream>>>(partial, out);
}